// Round 13
// baseline (613.754 us; speedup 1.0000x reference)
//
#include <hip/hip_runtime.h>
#include <hip/hip_fp16.h>

#define B_    256
#define CIN   128
#define CH    64
#define NPX   1024   // 32*32
#define NWIN  49
#define TROWS 22     // 16 tile rows + 3 halo each side
#define TCOLS 40     // 32 cols + 4 halo each side
#define CELLU 4      // uints per cell = 8 f16 channels = 16 B (benign 8-way banking)
#define BUFU  (TROWS * TCOLS * CELLU)   // 3520 uints = 14080 B per buffer
#define NEG_INF_F (-1e30f)

typedef _Float16 h2v __attribute__((ext_vector_type(2)));
typedef __fp16   p2v __attribute__((ext_vector_type(2)));   // cvt_pkrtz result type
typedef __fp16   p8v __attribute__((ext_vector_type(8)));   // mfma f16 operand type
typedef float    f4v __attribute__((ext_vector_type(4)));   // mfma acc type

#define FDOT2(a, b, c) __builtin_amdgcn_fdot2((a), (b), (c), false)

union CV { p2v p; h2v h; uint u; };
union U4 { int4 v; uint u[4]; h2v h[4]; };
union AF { uint4 u4; p8v h8; };

// acc(f32) += f16 half of vu * f16 half of pu — one v_fma_mix_f32.
#define FMIX(acc, vu, vh, pu, ph) do {                                                                              \
    if      ((vh) == 0 && (ph) == 0) asm("v_fma_mix_f32 %0, %1, %2, %0 op_sel:[0,0,0] op_sel_hi:[1,1,0]" : "+v"(acc) : "v"(vu), "v"(pu)); \
    else if ((vh) == 1 && (ph) == 0) asm("v_fma_mix_f32 %0, %1, %2, %0 op_sel:[1,0,0] op_sel_hi:[1,1,0]" : "+v"(acc) : "v"(vu), "v"(pu)); \
    else if ((vh) == 0 && (ph) == 1) asm("v_fma_mix_f32 %0, %1, %2, %0 op_sel:[0,1,0] op_sel_hi:[1,1,0]" : "+v"(acc) : "v"(vu), "v"(pu)); \
    else                             asm("v_fma_mix_f32 %0, %1, %2, %0 op_sel:[1,1,0] op_sel_hi:[1,1,0]" : "+v"(acc) : "v"(vu), "v"(pu)); \
} while (0)

// acc_pk(2xf16) += broadcast(half ph of pu) * vu(2xf16) — one v_pk_fma_f16.
#define PKFMA(accu, vu, pu, ph) do {                                                                                \
    if ((ph) == 0) asm("v_pk_fma_f16 %0, %2, %1, %0 op_sel:[0,0,0] op_sel_hi:[0,1,1]" : "+v"(accu) : "v"(vu), "v"(pu)); \
    else           asm("v_pk_fma_f16 %0, %2, %1, %0 op_sel:[1,0,0] op_sel_hi:[1,1,1]" : "+v"(accu) : "v"(vu), "v"(pu)); \
} while (0)

// a32(f32) += f16 half of pk — one v_fma_mix_f32 with inline 1.0.
#define FLUSHLO(a32, pk) asm("v_fma_mix_f32 %0, 1.0, %1, %0 op_sel:[0,0,0] op_sel_hi:[0,1,0]" : "+v"(a32) : "v"(pk))
#define FLUSHHI(a32, pk) asm("v_fma_mix_f32 %0, 1.0, %1, %0 op_sel:[0,1,0] op_sel_hi:[0,1,0]" : "+v"(a32) : "v"(pk))

// ---------------------------------------------------------------------------
// Pack W (Ch x Cin) into the EXACT A-fragment layout of mfma_f32_16x16x32_f16.
// ---------------------------------------------------------------------------
__global__ __launch_bounds__(256) void wtrans_kernel(
    const float* __restrict__ Wq, const float* __restrict__ Wk,
    const int* __restrict__ same_flag,
    uint* __restrict__ WAQ, uint* __restrict__ WAK)
{
    const float* Wsel = (same_flag[0] != 0) ? Wq : Wk;
    for (int idx = threadIdx.x; idx < 4096; idx += 256) {
        int j  = idx & 3;
        int l  = (idx >> 2) & 63;
        int ks = (idx >> 8) & 3;
        int mt = idx >> 10;
        int row = mt * 16 + (l & 15);
        int k0  = ks * 32 + ((l >> 4) << 3) + 2 * j;
        CV a; a.p = __builtin_amdgcn_cvt_pkrtz(Wq[row * CIN + k0], Wq[row * CIN + k0 + 1]);
        WAQ[idx] = a.u;
        CV b2; b2.p = __builtin_amdgcn_cvt_pkrtz(Wsel[row * CIN + k0], Wsel[row * CIN + k0 + 1]);
        WAK[idx] = b2.u;
    }
}

// ---------------------------------------------------------------------------
// MFMA conv, 32 px per wave (two B-frag sets share each A-frag load; 64
// loads in flight per wave). y=0: left -> Q AND K_left; y=1: right -> K_right.
// Bias rides in as the MFMA C operand. D layout (m89): col=lane&15=px,
// row=(lane>>4)*4+reg -> pair-packed stores.
// ---------------------------------------------------------------------------
__global__ __launch_bounds__(256) void convm_kernel(
    const float* __restrict__ left, const float* __restrict__ right,
    const uint* __restrict__ WAQ, const uint* __restrict__ WAK,
    const float* __restrict__ bq, const float* __restrict__ bk,
    const int* __restrict__ same_flag,
    uint* __restrict__ dQ, uint* __restrict__ dKL, uint* __restrict__ dKR)
{
    int t   = threadIdx.x;
    int l   = t & 63;
    int wv  = t >> 6;
    int img = blockIdx.x >> 3;
    int px0 = ((blockIdx.x & 7) << 7) + (wv << 5) + (l & 15);   // set 0; set 1 = +16
    int che = (l >> 4) << 3;               // k-group base channel offset
    int r0  = (l >> 4) << 2;               // C row base within tile
    const float* biasK = (same_flag[0] != 0) ? bq : bk;

    const float* xb = ((blockIdx.y == 0) ? left : right) + (size_t)img * (CIN * NPX);

    // B fragments: 2 px-sets x 4 k-steps x 8 f16
    AF bf[2][4];
#pragma unroll
    for (int s = 0; s < 2; ++s)
#pragma unroll
    for (int ks = 0; ks < 4; ++ks) {
        uint bu[4];
#pragma unroll
        for (int j = 0; j < 4; ++j) {
            int ch = ks * 32 + che + 2 * j;
            float x0 = xb[((size_t)ch << 10) + px0 + s * 16];
            float x1 = xb[((size_t)(ch + 1) << 10) + px0 + s * 16];
            CV c; c.p = __builtin_amdgcn_cvt_pkrtz(x0, x1);
            bu[j] = c.u;
        }
        bf[s][ks].u4 = make_uint4(bu[0], bu[1], bu[2], bu[3]);
    }

#define DOGEMM(WA, BIAS, DST)                                                   \
    {                                                                           \
      uint* dst = DST + (size_t)img * ((CH / 2) * NPX);                         \
      _Pragma("unroll") for (int mt = 0; mt < 4; ++mt) {                        \
        float4 bb = *(const float4*)((BIAS) + mt * 16 + r0);                    \
        f4v acc0 = { bb.x, bb.y, bb.z, bb.w };                                  \
        f4v acc1 = acc0;                                                        \
        _Pragma("unroll") for (int ks = 0; ks < 4; ++ks) {                      \
            AF wa; wa.u4 = *(const uint4*)((WA) + (((mt << 2) + ks) << 8) + (l << 2)); \
            acc0 = __builtin_amdgcn_mfma_f32_16x16x32_f16(wa.h8, bf[0][ks].h8, acc0, 0, 0, 0); \
            acc1 = __builtin_amdgcn_mfma_f32_16x16x32_f16(wa.h8, bf[1][ks].h8, acc1, 0, 0, 0); \
        }                                                                       \
        int cp = (mt << 3) + ((l >> 4) << 1);                                   \
        CV c0; c0.p = __builtin_amdgcn_cvt_pkrtz(acc0[0], acc0[1]);             \
        dst[((size_t)cp << 10) + px0] = c0.u;                                   \
        CV c1; c1.p = __builtin_amdgcn_cvt_pkrtz(acc0[2], acc0[3]);             \
        dst[((size_t)(cp + 1) << 10) + px0] = c1.u;                             \
        CV c2; c2.p = __builtin_amdgcn_cvt_pkrtz(acc1[0], acc1[1]);             \
        dst[((size_t)cp << 10) + px0 + 16] = c2.u;                              \
        CV c3; c3.p = __builtin_amdgcn_cvt_pkrtz(acc1[2], acc1[3]);             \
        dst[((size_t)(cp + 1) << 10) + px0 + 16] = c3.u;                        \
      }                                                                         \
    }

    if (blockIdx.y == 0) {
        DOGEMM(WAQ, bq,    dQ)
        DOGEMM(WAK, biasK, dKL)
    } else {
        DOGEMM(WAK, biasK, dKR)
    }
#undef DOGEMM
}

// ---------------------------------------------------------------------------
// attend2: round-11 structure, waves_per_eu(4,4): kernel needs 120 VGPR which
// fits the 128-reg/4-wave budget -> 2x occupancy (16 waves/CU) for pipe
// overlap. LDS 4 x 28.2 KB = 113 KB/CU. Spill tell: WRITE_SIZE > 262144 KB.
// ---------------------------------------------------------------------------
__global__ __launch_bounds__(256) __attribute__((amdgpu_waves_per_eu(4, 4)))
void attend2_kernel(
    const uint* __restrict__ Q, const uint* __restrict__ KR,
    const uint* __restrict__ KL,
    const float* __restrict__ right, const float* __restrict__ left,
    float* __restrict__ out, const int* __restrict__ self_flag)
{
    __shared__ __align__(16) uint buf[2 * BUFU];   // 28160 B

    int side = blockIdx.y;            // 0: right-attend, 1: left-attend
    int b    = blockIdx.x >> 1;
    int h0   = (blockIdx.x & 1) << 4;
    int t    = threadIdx.x;
    int w    = t & 31;
    int r2   = (t >> 5) << 1;         // 0,2,..,14
    int h    = h0 + r2;               // rows h and h+1
    int qoff = (h << 5) + w;
    int cb   = side ? 0 : CIN;

    const uint*  K = side ? KL : KR;
    const float* V = side ? left : right;

    if (side == 1 && self_flag[0] == 0) {
        const float* s = left + (size_t)b * (CIN * NPX) + qoff;
        float* d = out + (size_t)b * (2 * CIN * NPX) + qoff;
        for (int c = 0; c < CIN; ++c) {
            d[(size_t)c << 10] = s[(size_t)c << 10];
            d[((size_t)c << 10) + 32] = s[((size_t)c << 10) + 32];
        }
        return;
    }

    // ---- zero both buffers once (borders stay 0 through A and C) ----
#pragma unroll
    for (int i = 0; i < 7; ++i) {
        int idx = t + (i << 8);
        if (idx < 2 * BUFU / 4) ((int4*)buf)[idx] = int4{0, 0, 0, 0};
    }

    int rowlo = (h0 == 0) ? 0 : h0 - 3;   // first valid global row (19 staged)
    int rowof = (h0 == 0) ? 3 : 0;        // its LDS row
    int c2    = (t >> 5) & 3;             // staging channel-pair within group
    int rr    = t >> 7;                   // staging row parity

    const uint* Kb = K + (size_t)b * ((CH / 2) * NPX);
    const uint* Qb = Q + (size_t)b * ((CH / 2) * NPX);

    float sc0[NWIN], sc1[NWIN];
#pragma unroll
    for (int i = 0; i < NWIN; ++i) { sc0[i] = 0.f; sc1[i] = 0.f; }

#define ROWS_OK(i) (rr + 2 * (i) < 19)
#define PFK(g, arr)                                                            \
    _Pragma("unroll") for (int i = 0; i < 10; ++i) if (ROWS_OK(i))             \
        arr[i] = Kb[((size_t)((((g) << 2) + c2)) << 10) + ((rowlo + rr + 2 * i) << 5) + w];
#define WRK(bp, arr)                                                           \
    _Pragma("unroll") for (int i = 0; i < 10; ++i) if (ROWS_OK(i))             \
        (bp)[((rowof + rr + 2 * i) * TCOLS + (w + 4)) * CELLU + c2] = arr[i];

#define COMPA(bp, g) {                                                         \
    CV qa[4], qc[4];                                                           \
    _Pragma("unroll") for (int j = 0; j < 4; ++j) {                            \
        qa[j].u = Qb[((size_t)(((g) << 2) + j) << 10) + qoff];                 \
        qc[j].u = Qb[((size_t)(((g) << 2) + j) << 10) + qoff + 32];            \
    }                                                                          \
    _Pragma("unroll") for (int dh = 0; dh < 8; ++dh) {                         \
        int cu0 = ((r2 + dh) * TCOLS + (w + 1)) * CELLU;                       \
        _Pragma("unroll") for (int dw = 0; dw < 7; ++dw) {                     \
            U4 kk; kk.v = *(const int4*)((bp) + cu0 + dw * CELLU);             \
            if (dh < 7) {                                                      \
                float s = sc0[dh * 7 + dw];                                    \
                _Pragma("unroll") for (int j = 0; j < 4; ++j)                  \
                    s = FDOT2(kk.h[j], qa[j].h, s);                            \
                sc0[dh * 7 + dw] = s;                                          \
            }                                                                  \
            if (dh >= 1) {                                                     \
                float s = sc1[(dh - 1) * 7 + dw];                              \
                _Pragma("unroll") for (int j = 0; j < 4; ++j)                  \
                    s = FDOT2(kk.h[j], qc[j].h, s);                            \
                sc1[(dh - 1) * 7 + dw] = s;                                    \
            }                                                                  \
        }                                                                      \
    } }

    // ---- Phase A: 8 groups of 8 ch, processed in dbuf pairs ----
    {
        uint pfa[10], pfb[10];
        PFK(0, pfa); PFK(1, pfb);
#pragma unroll 1
        for (int gp = 0; gp < 4; ++gp) {
            __syncthreads();                 // prior compute / zero-fill done
            WRK(buf, pfa); WRK(buf + BUFU, pfb);
            if (gp < 3) { PFK(2 * gp + 2, pfa); PFK(2 * gp + 3, pfb); }
            __syncthreads();                 // staged data visible
            COMPA(buf, 2 * gp);
            COMPA(buf + BUFU, 2 * gp + 1);
        }
    }

    // ---- masked softmax per pixel; weights packed to f16 pairs ----
    uint ph0[25], ph1[25];
    {
        float m = NEG_INF_F;
#pragma unroll
        for (int dh = 0; dh < 7; ++dh)
#pragma unroll
            for (int dw = 0; dw < 7; ++dw) {
                int i = dh * 7 + dw;
                bool vld = ((unsigned)(h + dh - 3) < 32u) && ((unsigned)(w + dw - 3) < 32u);
                sc0[i] = vld ? sc0[i] : NEG_INF_F;
                m = fmaxf(m, sc0[i]);
            }
        float ssum = 0.f;
#pragma unroll
        for (int i = 0; i < NWIN; ++i) { sc0[i] = __expf(sc0[i] - m); ssum += sc0[i]; }
        float inv = 1.f / ssum;
#pragma unroll
        for (int j = 0; j < 24; ++j) {
            CV cv; cv.p = __builtin_amdgcn_cvt_pkrtz(sc0[2 * j] * inv, sc0[2 * j + 1] * inv);
            ph0[j] = cv.u;
        }
        CV cv; cv.p = __builtin_amdgcn_cvt_pkrtz(sc0[48] * inv, 0.f);
        ph0[24] = cv.u;
    }
    {
        float m = NEG_INF_F;
#pragma unroll
        for (int dh = 0; dh < 7; ++dh)
#pragma unroll
            for (int dw = 0; dw < 7; ++dw) {
                int i = dh * 7 + dw;
                bool vld = ((unsigned)(h + 1 + dh - 3) < 32u) && ((unsigned)(w + dw - 3) < 32u);
                sc1[i] = vld ? sc1[i] : NEG_INF_F;
                m = fmaxf(m, sc1[i]);
            }
        float ssum = 0.f;
#pragma unroll
        for (int i = 0; i < NWIN; ++i) { sc1[i] = __expf(sc1[i] - m); ssum += sc1[i]; }
        float inv = 1.f / ssum;
#pragma unroll
        for (int j = 0; j < 24; ++j) {
            CV cv; cv.p = __builtin_amdgcn_cvt_pkrtz(sc1[2 * j] * inv, sc1[2 * j + 1] * inv);
            ph1[j] = cv.u;
        }
        CV cv; cv.p = __builtin_amdgcn_cvt_pkrtz(sc1[48] * inv, 0.f);
        ph1[24] = cv.u;
    }

    // ---- Phase C: 16 groups of 8 ch, pk_fma + f32 flush, 1 barrier/group ----
    const float* Vb = V + (size_t)b * (CIN * NPX);
    float* ob = out + (size_t)b * (2 * CIN * NPX) + ((size_t)cb << 10) + qoff;

    float pv0[10], pv1[10];
#define PFV(vg) {                                                              \
    const float* va = Vb + ((size_t)((((vg) << 2) + c2) * 2) << 10);           \
    const float* vc = va + NPX;                                                \
    _Pragma("unroll") for (int i = 0; i < 10; ++i) if (ROWS_OK(i)) {           \
        int gi = ((rowlo + rr + 2 * i) << 5) + w;                              \
        pv0[i] = va[gi]; pv1[i] = vc[gi];                                      \
    } }
#define WRV(bp)                                                                \
    _Pragma("unroll") for (int i = 0; i < 10; ++i) if (ROWS_OK(i)) {           \
        CV cv; cv.p = __builtin_amdgcn_cvt_pkrtz(pv0[i], pv1[i]);              \
        (bp)[((rowof + rr + 2 * i) * TCOLS + (w + 4)) * CELLU + c2] = cv.u;    \
    }

    PFV(0);
    __syncthreads();                     // phase-A reads of both buffers done
    WRV(buf);                            // group 0 -> buf0

#pragma unroll 1
    for (int vg = 0; vg < 16; ++vg) {
        if (vg < 15) PFV(vg + 1);        // issue next group's loads early
        __syncthreads();                 // current group's writes visible

        const uint* bp = buf + (vg & 1) * BUFU;
        float a0[8], a1[8];
#pragma unroll
        for (int c = 0; c < 8; ++c) { a0[c] = 0.f; a1[c] = 0.f; }
        uint pk0[4], pk1[4];
#pragma unroll
        for (int j = 0; j < 4; ++j) { pk0[j] = 0u; pk1[j] = 0u; }

#pragma unroll
        for (int dh = 0; dh < 8; ++dh) {
            int cu0 = ((r2 + dh) * TCOLS + (w + 1)) * CELLU;
#pragma unroll
            for (int dw = 0; dw < 7; ++dw) {
                U4 kk; kk.v = *(const int4*)(bp + cu0 + dw * CELLU);
                if (dh < 7) {
                    int tp = dh * 7 + dw;
#pragma unroll
                    for (int j = 0; j < 4; ++j)
                        PKFMA(pk0[j], kk.u[j], ph0[tp >> 1], (tp & 1));
                }
                if (dh >= 1) {
                    int tp = (dh - 1) * 7 + dw;
#pragma unroll
                    for (int j = 0; j < 4; ++j)
                        PKFMA(pk1[j], kk.u[j], ph1[tp >> 1], (tp & 1));
                }
            }
            if (dh & 1) {                // flush f16 partials every 2 dh rows
#pragma unroll
                for (int j = 0; j < 4; ++j) {
                    FLUSHLO(a0[2 * j], pk0[j]); FLUSHHI(a0[2 * j + 1], pk0[j]); pk0[j] = 0u;
                    FLUSHLO(a1[2 * j], pk1[j]); FLUSHHI(a1[2 * j + 1], pk1[j]); pk1[j] = 0u;
                }
            }
        }

        if (vg < 15) WRV(buf + ((vg + 1) & 1) * BUFU);   // stage next group

#pragma unroll
        for (int c = 0; c < 8; ++c) {
            ob[((size_t)((vg << 3) + c)) << 10] = a0[c];
            ob[(((size_t)((vg << 3) + c)) << 10) + 32] = a1[c];
        }
    }
}

// ---------------------------------------------------------------------------
// 3 launches: wtrans -> convm (4096 blocks) -> attend2 (1024 blocks).
// ws: 3 x 32 MiB pair-packed f16 (Q, K_left, K_right) + 2 A-frag W = 96.03 MiB.
// ---------------------------------------------------------------------------
extern "C" void kernel_launch(void* const* d_in, const int* in_sizes, int n_in,
                              void* d_out, int out_size, void* d_ws, size_t ws_size,
                              hipStream_t stream)
{
    (void)in_sizes; (void)n_in; (void)out_size; (void)ws_size;

    const float* left  = (const float*)d_in[0];
    const float* right = (const float*)d_in[1];
    const float* Wq    = (const float*)d_in[2];
    const float* bq    = (const float*)d_in[3];
    const float* Wk    = (const float*)d_in[4];
    const float* bk    = (const float*)d_in[5];
    const int* self_flag = (const int*)d_in[7];
    const int* same_flag = (const int*)d_in[8];

    uint* wsQ  = (uint*)d_ws;                              // 32 MiB
    uint* wsKL = wsQ  + (size_t)B_ * (CH / 2) * NPX;       // 32 MiB
    uint* wsKR = wsKL + (size_t)B_ * (CH / 2) * NPX;       // 32 MiB
    uint* WAQ  = wsKR + (size_t)B_ * (CH / 2) * NPX;       // 4096 uints
    uint* WAK  = WAQ + 4096;

    float* out = (float*)d_out;

    wtrans_kernel<<<1, 256, 0, stream>>>(Wq, Wk, same_flag, WAQ, WAK);

    convm_kernel<<<dim3(B_ * 8, 2), 256, 0, stream>>>(
        left, right, WAQ, WAK, bq, bk, same_flag, wsQ, wsKL, wsKR);

    attend2_kernel<<<dim3(B_ * 2, 2), 256, 0, stream>>>(
        wsQ, wsKR, wsKL, right, left, out, self_flag);
}

// Round 14
// 248.288 us; speedup vs baseline: 2.4719x; 2.4719x over previous
//
#include <hip/hip_runtime.h>
#include <hip/hip_fp16.h>

#define B_    256
#define CIN   128
#define CH    64
#define NPX   1024   // 32*32
#define NWIN  49
#define TROWS 22     // 16 tile rows + 3 halo each side
#define TCOLS 40     // 32 cols + 4 halo each side
#define CELLU 4      // uints per cell = 8 f16 channels = 16 B (benign 8-way banking)
#define BUFU  (TROWS * TCOLS * CELLU)   // 3520 uints = 14080 B per buffer
#define NEG_INF_F (-1e30f)

typedef _Float16 h2v __attribute__((ext_vector_type(2)));
typedef __fp16   p2v __attribute__((ext_vector_type(2)));   // cvt_pkrtz result type
typedef __fp16   p8v __attribute__((ext_vector_type(8)));   // mfma f16 operand type
typedef float    f4v __attribute__((ext_vector_type(4)));   // mfma acc type

#define FDOT2(a, b, c) __builtin_amdgcn_fdot2((a), (b), (c), false)

union CV { p2v p; h2v h; uint u; };
union U4 { int4 v; uint u[4]; h2v h[4]; };
union AF { uint4 u4; p8v h8; };

// acc(f32) += f16 half of vu * f16 half of pu — one v_fma_mix_f32.
#define FMIX(acc, vu, vh, pu, ph) do {                                                                              \
    if      ((vh) == 0 && (ph) == 0) asm("v_fma_mix_f32 %0, %1, %2, %0 op_sel:[0,0,0] op_sel_hi:[1,1,0]" : "+v"(acc) : "v"(vu), "v"(pu)); \
    else if ((vh) == 1 && (ph) == 0) asm("v_fma_mix_f32 %0, %1, %2, %0 op_sel:[1,0,0] op_sel_hi:[1,1,0]" : "+v"(acc) : "v"(vu), "v"(pu)); \
    else if ((vh) == 0 && (ph) == 1) asm("v_fma_mix_f32 %0, %1, %2, %0 op_sel:[0,1,0] op_sel_hi:[1,1,0]" : "+v"(acc) : "v"(vu), "v"(pu)); \
    else                             asm("v_fma_mix_f32 %0, %1, %2, %0 op_sel:[1,1,0] op_sel_hi:[1,1,0]" : "+v"(acc) : "v"(vu), "v"(pu)); \
} while (0)

// acc_pk(2xf16) += broadcast(half ph of pu) * vu(2xf16) — one v_pk_fma_f16.
#define PKFMA(accu, vu, pu, ph) do {                                                                                \
    if ((ph) == 0) asm("v_pk_fma_f16 %0, %2, %1, %0 op_sel:[0,0,0] op_sel_hi:[0,1,1]" : "+v"(accu) : "v"(vu), "v"(pu)); \
    else           asm("v_pk_fma_f16 %0, %2, %1, %0 op_sel:[1,0,0] op_sel_hi:[1,1,1]" : "+v"(accu) : "v"(vu), "v"(pu)); \
} while (0)

// a32(f32) += f16 half of pk — one v_fma_mix_f32 with inline 1.0.
#define FLUSHLO(a32, pk) asm("v_fma_mix_f32 %0, 1.0, %1, %0 op_sel:[0,0,0] op_sel_hi:[0,1,0]" : "+v"(a32) : "v"(pk))
#define FLUSHHI(a32, pk) asm("v_fma_mix_f32 %0, 1.0, %1, %0 op_sel:[0,1,0] op_sel_hi:[0,1,0]" : "+v"(a32) : "v"(pk))

// ---------------------------------------------------------------------------
// Pack W (Ch x Cin) into the EXACT A-fragment layout of mfma_f32_16x16x32_f16.
// ---------------------------------------------------------------------------
__global__ __launch_bounds__(256) void wtrans_kernel(
    const float* __restrict__ Wq, const float* __restrict__ Wk,
    const int* __restrict__ same_flag,
    uint* __restrict__ WAQ, uint* __restrict__ WAK)
{
    const float* Wsel = (same_flag[0] != 0) ? Wq : Wk;
    for (int idx = threadIdx.x; idx < 4096; idx += 256) {
        int j  = idx & 3;
        int l  = (idx >> 2) & 63;
        int ks = (idx >> 8) & 3;
        int mt = idx >> 10;
        int row = mt * 16 + (l & 15);
        int k0  = ks * 32 + ((l >> 4) << 3) + 2 * j;
        CV a; a.p = __builtin_amdgcn_cvt_pkrtz(Wq[row * CIN + k0], Wq[row * CIN + k0 + 1]);
        WAQ[idx] = a.u;
        CV b2; b2.p = __builtin_amdgcn_cvt_pkrtz(Wsel[row * CIN + k0], Wsel[row * CIN + k0 + 1]);
        WAK[idx] = b2.u;
    }
}

// ---------------------------------------------------------------------------
// MFMA conv, 32 px per wave (round-13 version, measured ~83 us): two B-frag
// sets share each A-frag load; 64 loads in flight per wave. y=0: left -> Q
// AND K_left; y=1: right -> K_right. Bias rides in as the MFMA C operand.
// D layout (m89): col=lane&15=px, row=(lane>>4)*4+reg -> pair-packed stores.
// ---------------------------------------------------------------------------
__global__ __launch_bounds__(256) void convm_kernel(
    const float* __restrict__ left, const float* __restrict__ right,
    const uint* __restrict__ WAQ, const uint* __restrict__ WAK,
    const float* __restrict__ bq, const float* __restrict__ bk,
    const int* __restrict__ same_flag,
    uint* __restrict__ dQ, uint* __restrict__ dKL, uint* __restrict__ dKR)
{
    int t   = threadIdx.x;
    int l   = t & 63;
    int wv  = t >> 6;
    int img = blockIdx.x >> 3;
    int px0 = ((blockIdx.x & 7) << 7) + (wv << 5) + (l & 15);   // set 0; set 1 = +16
    int che = (l >> 4) << 3;               // k-group base channel offset
    int r0  = (l >> 4) << 2;               // C row base within tile
    const float* biasK = (same_flag[0] != 0) ? bq : bk;

    const float* xb = ((blockIdx.y == 0) ? left : right) + (size_t)img * (CIN * NPX);

    // B fragments: 2 px-sets x 4 k-steps x 8 f16
    AF bf[2][4];
#pragma unroll
    for (int s = 0; s < 2; ++s)
#pragma unroll
    for (int ks = 0; ks < 4; ++ks) {
        uint bu[4];
#pragma unroll
        for (int j = 0; j < 4; ++j) {
            int ch = ks * 32 + che + 2 * j;
            float x0 = xb[((size_t)ch << 10) + px0 + s * 16];
            float x1 = xb[((size_t)(ch + 1) << 10) + px0 + s * 16];
            CV c; c.p = __builtin_amdgcn_cvt_pkrtz(x0, x1);
            bu[j] = c.u;
        }
        bf[s][ks].u4 = make_uint4(bu[0], bu[1], bu[2], bu[3]);
    }

#define DOGEMM(WA, BIAS, DST)                                                   \
    {                                                                           \
      uint* dst = DST + (size_t)img * ((CH / 2) * NPX);                         \
      _Pragma("unroll") for (int mt = 0; mt < 4; ++mt) {                        \
        float4 bb = *(const float4*)((BIAS) + mt * 16 + r0);                    \
        f4v acc0 = { bb.x, bb.y, bb.z, bb.w };                                  \
        f4v acc1 = acc0;                                                        \
        _Pragma("unroll") for (int ks = 0; ks < 4; ++ks) {                      \
            AF wa; wa.u4 = *(const uint4*)((WA) + (((mt << 2) + ks) << 8) + (l << 2)); \
            acc0 = __builtin_amdgcn_mfma_f32_16x16x32_f16(wa.h8, bf[0][ks].h8, acc0, 0, 0, 0); \
            acc1 = __builtin_amdgcn_mfma_f32_16x16x32_f16(wa.h8, bf[1][ks].h8, acc1, 0, 0, 0); \
        }                                                                       \
        int cp = (mt << 3) + ((l >> 4) << 1);                                   \
        CV c0; c0.p = __builtin_amdgcn_cvt_pkrtz(acc0[0], acc0[1]);             \
        dst[((size_t)cp << 10) + px0] = c0.u;                                   \
        CV c1; c1.p = __builtin_amdgcn_cvt_pkrtz(acc0[2], acc0[3]);             \
        dst[((size_t)(cp + 1) << 10) + px0] = c1.u;                             \
        CV c2; c2.p = __builtin_amdgcn_cvt_pkrtz(acc1[0], acc1[1]);             \
        dst[((size_t)cp << 10) + px0 + 16] = c2.u;                              \
        CV c3; c3.p = __builtin_amdgcn_cvt_pkrtz(acc1[2], acc1[3]);             \
        dst[((size_t)(cp + 1) << 10) + px0 + 16] = c3.u;                        \
      }                                                                         \
    }

    if (blockIdx.y == 0) {
        DOGEMM(WAQ, bq,    dQ)
        DOGEMM(WAK, biasK, dKL)
    } else {
        DOGEMM(WAK, biasK, dKR)
    }
#undef DOGEMM
}

// ---------------------------------------------------------------------------
// attend2: EXACT round-12 config (measured 166.5 us twice). waves_per_eu(2,2)
// is the empirically-only-safe allocator pin (VGPR 120, zero spill); any
// higher waves floor makes the allocator halve the register file and spill.
// ---------------------------------------------------------------------------
__global__ __launch_bounds__(256) __attribute__((amdgpu_waves_per_eu(2, 2)))
void attend2_kernel(
    const uint* __restrict__ Q, const uint* __restrict__ KR,
    const uint* __restrict__ KL,
    const float* __restrict__ right, const float* __restrict__ left,
    float* __restrict__ out, const int* __restrict__ self_flag)
{
    __shared__ __align__(16) uint buf[2 * BUFU];   // 28160 B

    int side = blockIdx.y;            // 0: right-attend, 1: left-attend
    int b    = blockIdx.x >> 1;
    int h0   = (blockIdx.x & 1) << 4;
    int t    = threadIdx.x;
    int w    = t & 31;
    int r2   = (t >> 5) << 1;         // 0,2,..,14
    int h    = h0 + r2;               // rows h and h+1
    int qoff = (h << 5) + w;
    int cb   = side ? 0 : CIN;

    const uint*  K = side ? KL : KR;
    const float* V = side ? left : right;

    if (side == 1 && self_flag[0] == 0) {
        const float* s = left + (size_t)b * (CIN * NPX) + qoff;
        float* d = out + (size_t)b * (2 * CIN * NPX) + qoff;
        for (int c = 0; c < CIN; ++c) {
            d[(size_t)c << 10] = s[(size_t)c << 10];
            d[((size_t)c << 10) + 32] = s[((size_t)c << 10) + 32];
        }
        return;
    }

    // ---- zero both buffers once (borders stay 0 through A and C) ----
#pragma unroll
    for (int i = 0; i < 7; ++i) {
        int idx = t + (i << 8);
        if (idx < 2 * BUFU / 4) ((int4*)buf)[idx] = int4{0, 0, 0, 0};
    }

    int rowlo = (h0 == 0) ? 0 : h0 - 3;   // first valid global row (19 staged)
    int rowof = (h0 == 0) ? 3 : 0;        // its LDS row
    int c2    = (t >> 5) & 3;             // staging channel-pair within group
    int rr    = t >> 7;                   // staging row parity

    const uint* Kb = K + (size_t)b * ((CH / 2) * NPX);
    const uint* Qb = Q + (size_t)b * ((CH / 2) * NPX);

    float sc0[NWIN], sc1[NWIN];
#pragma unroll
    for (int i = 0; i < NWIN; ++i) { sc0[i] = 0.f; sc1[i] = 0.f; }

#define ROWS_OK(i) (rr + 2 * (i) < 19)
#define PFK(g, arr)                                                            \
    _Pragma("unroll") for (int i = 0; i < 10; ++i) if (ROWS_OK(i))             \
        arr[i] = Kb[((size_t)((((g) << 2) + c2)) << 10) + ((rowlo + rr + 2 * i) << 5) + w];
#define WRK(bp, arr)                                                           \
    _Pragma("unroll") for (int i = 0; i < 10; ++i) if (ROWS_OK(i))             \
        (bp)[((rowof + rr + 2 * i) * TCOLS + (w + 4)) * CELLU + c2] = arr[i];

#define COMPA(bp, g) {                                                         \
    CV qa[4], qc[4];                                                           \
    _Pragma("unroll") for (int j = 0; j < 4; ++j) {                            \
        qa[j].u = Qb[((size_t)(((g) << 2) + j) << 10) + qoff];                 \
        qc[j].u = Qb[((size_t)(((g) << 2) + j) << 10) + qoff + 32];            \
    }                                                                          \
    _Pragma("unroll") for (int dh = 0; dh < 8; ++dh) {                         \
        int cu0 = ((r2 + dh) * TCOLS + (w + 1)) * CELLU;                       \
        _Pragma("unroll") for (int dw = 0; dw < 7; ++dw) {                     \
            U4 kk; kk.v = *(const int4*)((bp) + cu0 + dw * CELLU);             \
            if (dh < 7) {                                                      \
                float s = sc0[dh * 7 + dw];                                    \
                _Pragma("unroll") for (int j = 0; j < 4; ++j)                  \
                    s = FDOT2(kk.h[j], qa[j].h, s);                            \
                sc0[dh * 7 + dw] = s;                                          \
            }                                                                  \
            if (dh >= 1) {                                                     \
                float s = sc1[(dh - 1) * 7 + dw];                              \
                _Pragma("unroll") for (int j = 0; j < 4; ++j)                  \
                    s = FDOT2(kk.h[j], qc[j].h, s);                            \
                sc1[(dh - 1) * 7 + dw] = s;                                    \
            }                                                                  \
        }                                                                      \
    } }

    // ---- Phase A: 8 groups of 8 ch, processed in dbuf pairs ----
    {
        uint pfa[10], pfb[10];
        PFK(0, pfa); PFK(1, pfb);
#pragma unroll 1
        for (int gp = 0; gp < 4; ++gp) {
            __syncthreads();                 // prior compute / zero-fill done
            WRK(buf, pfa); WRK(buf + BUFU, pfb);
            if (gp < 3) { PFK(2 * gp + 2, pfa); PFK(2 * gp + 3, pfb); }
            __syncthreads();                 // staged data visible
            COMPA(buf, 2 * gp);
            COMPA(buf + BUFU, 2 * gp + 1);
        }
    }

    // ---- masked softmax per pixel; weights packed to f16 pairs ----
    uint ph0[25], ph1[25];
    {
        float m = NEG_INF_F;
#pragma unroll
        for (int dh = 0; dh < 7; ++dh)
#pragma unroll
            for (int dw = 0; dw < 7; ++dw) {
                int i = dh * 7 + dw;
                bool vld = ((unsigned)(h + dh - 3) < 32u) && ((unsigned)(w + dw - 3) < 32u);
                sc0[i] = vld ? sc0[i] : NEG_INF_F;
                m = fmaxf(m, sc0[i]);
            }
        float ssum = 0.f;
#pragma unroll
        for (int i = 0; i < NWIN; ++i) { sc0[i] = __expf(sc0[i] - m); ssum += sc0[i]; }
        float inv = 1.f / ssum;
#pragma unroll
        for (int j = 0; j < 24; ++j) {
            CV cv; cv.p = __builtin_amdgcn_cvt_pkrtz(sc0[2 * j] * inv, sc0[2 * j + 1] * inv);
            ph0[j] = cv.u;
        }
        CV cv; cv.p = __builtin_amdgcn_cvt_pkrtz(sc0[48] * inv, 0.f);
        ph0[24] = cv.u;
    }
    {
        float m = NEG_INF_F;
#pragma unroll
        for (int dh = 0; dh < 7; ++dh)
#pragma unroll
            for (int dw = 0; dw < 7; ++dw) {
                int i = dh * 7 + dw;
                bool vld = ((unsigned)(h + 1 + dh - 3) < 32u) && ((unsigned)(w + dw - 3) < 32u);
                sc1[i] = vld ? sc1[i] : NEG_INF_F;
                m = fmaxf(m, sc1[i]);
            }
        float ssum = 0.f;
#pragma unroll
        for (int i = 0; i < NWIN; ++i) { sc1[i] = __expf(sc1[i] - m); ssum += sc1[i]; }
        float inv = 1.f / ssum;
#pragma unroll
        for (int j = 0; j < 24; ++j) {
            CV cv; cv.p = __builtin_amdgcn_cvt_pkrtz(sc1[2 * j] * inv, sc1[2 * j + 1] * inv);
            ph1[j] = cv.u;
        }
        CV cv; cv.p = __builtin_amdgcn_cvt_pkrtz(sc1[48] * inv, 0.f);
        ph1[24] = cv.u;
    }

    // ---- Phase C: 16 groups of 8 ch, pk_fma + f32 flush, 1 barrier/group ----
    const float* Vb = V + (size_t)b * (CIN * NPX);
    float* ob = out + (size_t)b * (2 * CIN * NPX) + ((size_t)cb << 10) + qoff;

    float pv0[10], pv1[10];
#define PFV(vg) {                                                              \
    const float* va = Vb + ((size_t)((((vg) << 2) + c2) * 2) << 10);           \
    const float* vc = va + NPX;                                                \
    _Pragma("unroll") for (int i = 0; i < 10; ++i) if (ROWS_OK(i)) {           \
        int gi = ((rowlo + rr + 2 * i) << 5) + w;                              \
        pv0[i] = va[gi]; pv1[i] = vc[gi];                                      \
    } }
#define WRV(bp)                                                                \
    _Pragma("unroll") for (int i = 0; i < 10; ++i) if (ROWS_OK(i)) {           \
        CV cv; cv.p = __builtin_amdgcn_cvt_pkrtz(pv0[i], pv1[i]);              \
        (bp)[((rowof + rr + 2 * i) * TCOLS + (w + 4)) * CELLU + c2] = cv.u;    \
    }

    PFV(0);
    __syncthreads();                     // phase-A reads of both buffers done
    WRV(buf);                            // group 0 -> buf0

#pragma unroll 1
    for (int vg = 0; vg < 16; ++vg) {
        if (vg < 15) PFV(vg + 1);        // issue next group's loads early
        __syncthreads();                 // current group's writes visible

        const uint* bp = buf + (vg & 1) * BUFU;
        float a0[8], a1[8];
#pragma unroll
        for (int c = 0; c < 8; ++c) { a0[c] = 0.f; a1[c] = 0.f; }
        uint pk0[4], pk1[4];
#pragma unroll
        for (int j = 0; j < 4; ++j) { pk0[j] = 0u; pk1[j] = 0u; }

#pragma unroll
        for (int dh = 0; dh < 8; ++dh) {
            int cu0 = ((r2 + dh) * TCOLS + (w + 1)) * CELLU;
#pragma unroll
            for (int dw = 0; dw < 7; ++dw) {
                U4 kk; kk.v = *(const int4*)(bp + cu0 + dw * CELLU);
                if (dh < 7) {
                    int tp = dh * 7 + dw;
#pragma unroll
                    for (int j = 0; j < 4; ++j)
                        PKFMA(pk0[j], kk.u[j], ph0[tp >> 1], (tp & 1));
                }
                if (dh >= 1) {
                    int tp = (dh - 1) * 7 + dw;
#pragma unroll
                    for (int j = 0; j < 4; ++j)
                        PKFMA(pk1[j], kk.u[j], ph1[tp >> 1], (tp & 1));
                }
            }
            if (dh & 1) {                // flush f16 partials every 2 dh rows
#pragma unroll
                for (int j = 0; j < 4; ++j) {
                    FLUSHLO(a0[2 * j], pk0[j]); FLUSHHI(a0[2 * j + 1], pk0[j]); pk0[j] = 0u;
                    FLUSHLO(a1[2 * j], pk1[j]); FLUSHHI(a1[2 * j + 1], pk1[j]); pk1[j] = 0u;
                }
            }
        }

        if (vg < 15) WRV(buf + ((vg + 1) & 1) * BUFU);   // stage next group

#pragma unroll
        for (int c = 0; c < 8; ++c) {
            ob[((size_t)((vg << 3) + c)) << 10] = a0[c];
            ob[(((size_t)((vg << 3) + c)) << 10) + 32] = a1[c];
        }
    }
}

// ---------------------------------------------------------------------------
// 3 launches: wtrans -> convm (4096 blocks) -> attend2 (1024 blocks).
// ws: 3 x 32 MiB pair-packed f16 (Q, K_left, K_right) + 2 A-frag W = 96.03 MiB.
// ---------------------------------------------------------------------------
extern "C" void kernel_launch(void* const* d_in, const int* in_sizes, int n_in,
                              void* d_out, int out_size, void* d_ws, size_t ws_size,
                              hipStream_t stream)
{
    (void)in_sizes; (void)n_in; (void)out_size; (void)ws_size;

    const float* left  = (const float*)d_in[0];
    const float* right = (const float*)d_in[1];
    const float* Wq    = (const float*)d_in[2];
    const float* bq    = (const float*)d_in[3];
    const float* Wk    = (const float*)d_in[4];
    const float* bk    = (const float*)d_in[5];
    const int* self_flag = (const int*)d_in[7];
    const int* same_flag = (const int*)d_in[8];

    uint* wsQ  = (uint*)d_ws;                              // 32 MiB
    uint* wsKL = wsQ  + (size_t)B_ * (CH / 2) * NPX;       // 32 MiB
    uint* wsKR = wsKL + (size_t)B_ * (CH / 2) * NPX;       // 32 MiB
    uint* WAQ  = wsKR + (size_t)B_ * (CH / 2) * NPX;       // 4096 uints
    uint* WAK  = WAQ + 4096;

    float* out = (float*)d_out;

    wtrans_kernel<<<1, 256, 0, stream>>>(Wq, Wk, same_flag, WAQ, WAK);

    convm_kernel<<<dim3(B_ * 8, 2), 256, 0, stream>>>(
        left, right, WAQ, WAK, bq, bk, same_flag, wsQ, wsKL, wsKR);

    attend2_kernel<<<dim3(B_ * 2, 2), 256, 0, stream>>>(
        wsQ, wsKR, wsKL, right, left, out, self_flag);
}